// Round 5
// baseline (726.221 us; speedup 1.0000x reference)
//
#include <hip/hip_runtime.h>

// 3x3 reflect-padded patch extraction.
// x: [8, 256, 256, 32] f32  ->  out: [8, 256, 256, 288] f32
// out[b,h,w, c*9 + i] = x[b, refl(h + i/3 - 1), refl(w + i%3 - 1), c]
//
// v7: zero-LDS direct-store pipeline.
// Key observation: thread (p, cg) holds ALL inputs for output floats
// [pixel p][cg*36 .. cg*36+36) -- 36 CONTIGUOUS output floats (channels
// cg*4..cg*4+3, all 9 taps). So the repacked 9 float4s can be stored
// straight to global: addr = pixel*1152 + cg*144 + m*16. Across the wave
// each store instr is a stride-144 16B scatter, but each thread's 9
// back-to-back stores fully dirty its 144B span, and L2's byte-granular
// dirty masks assemble full 64B lines before eviction -> HBM still sees a
// full-line write stream. This removes the entire LDS round-trip
// (ds_write -> lgkmcnt -> ds_read -> lgkmcnt) that serialized every store
// burst in v3-v6, and with LDS gone occupancy doubles (VGPR-bound,
// ~8 waves/SIMD vs 4 LDS-capped).
// Regular (non-nt) stores: partial-line writes MUST be allowed to combine
// in L2; nt no-allocate would risk read-modify-write at HBM.

#define BB 8
#define HH 256
#define WW 256
#define CC 32
#define TAPS 9
#define OUTC (CC * TAPS)    // 288
#define TW 32               // w-tile per block
#define NTW (WW / TW)       // 8 tiles per row

typedef float f32x4 __attribute__((ext_vector_type(4)));

__device__ __forceinline__ int refl(int i, int n) {
    // np.pad mode='reflect', valid for i in [-1, n]
    return i < 0 ? -i : (i >= n ? 2 * n - 2 - i : i);
}

__global__ __launch_bounds__(256) void patch3x3_v7(
    const float* __restrict__ x, float* __restrict__ out) {
    const int blk = blockIdx.x;
    const int wt = blk % NTW;
    const int h  = (blk / NTW) % HH;
    const int b  = blk / (NTW * HH);
    const int w0 = wt * TW;
    const int t  = threadIdx.x;

    const int p  = t >> 3;      // pixel in tile, 0..31
    const int cg = t & 7;       // channel group of 4, 0..7

    // ---- tap gather straight from global (wave-uniform row bases) ----
    const float* xb = x + (size_t)b * HH * WW * CC;
    const float* row0 = xb + (size_t)refl(h - 1, HH) * WW * CC;
    const float* row1 = xb + (size_t)h * WW * CC;
    const float* row2 = xb + (size_t)refl(h + 1, HH) * WW * CC;

    int coff[3];
#pragma unroll
    for (int kj = 0; kj < 3; ++kj)
        coff[kj] = refl(w0 + p + kj - 1, WW) * CC + cg * 4;

    f32x4 q[3][3];
#pragma unroll
    for (int kj = 0; kj < 3; ++kj) {
        q[0][kj] = *(const f32x4*)(row0 + coff[kj]);
        q[1][kj] = *(const f32x4*)(row1 + coff[kj]);
        q[2][kj] = *(const f32x4*)(row2 + coff[kj]);
    }

    // ---- repack (pure register selects) + DIRECT global stores ----
    // This thread owns 36 contiguous output floats at
    // out[b,h,w0+p, cg*36 .. cg*36+36): 9 float4 stores, imm offsets.
    // local flat f = cl*9 + i, cl in [0,4), i = 3*ki + kj
    float* outp = out + (size_t)((b * HH + h) * WW + w0 + p) * OUTC + cg * 36;
#pragma unroll
    for (int m = 0; m < 9; ++m) {
        f32x4 v;
#pragma unroll
        for (int k = 0; k < 4; ++k) {
            const int f  = 4 * m + k;   // compile-time
            const int cl = f / 9;
            const int i  = f % 9;
            const int ki = i / 3;
            const int kj = i % 3;
            v[k] = q[ki][kj][cl];
        }
        *(f32x4*)(outp + 4 * m) = v;
    }
}

extern "C" void kernel_launch(void* const* d_in, const int* in_sizes, int n_in,
                              void* d_out, int out_size, void* d_ws, size_t ws_size,
                              hipStream_t stream) {
    const float* x = (const float*)d_in[0];
    float* out = (float*)d_out;
    const int nblocks = BB * HH * NTW;   // 16384
    patch3x3_v7<<<nblocks, 256, 0, stream>>>(x, out);
}